// Round 5
// baseline (137.159 us; speedup 1.0000x reference)
//
#include <hip/hip_runtime.h>

#define BATCH  8
#define CH     64
#define H      128
#define W      128
#define HW     (H * W)             // 16384
#define RS     8                   // rows per wave strip
#define CPW    2                   // channels per wave
#define NSTRIP (H / RS)            // 16

typedef float vfloat2 __attribute__((ext_vector_type(2)));
typedef float vfloat4 __attribute__((ext_vector_type(4)));

__device__ __forceinline__ float sigmoidf_(float v) {
    return 1.0f / (1.0f + __expf(-v));
}

// D_k = max(wk, p_k) + bk over 3x3 window; out = wc*center + wm*median - sum - sum/9
__device__ __forceinline__ float pixel_val(
    const float p0, const float p1, const float p2,
    const float p3, const float p4, const float p5,
    const float p6, const float p7, const float p8,
    const float* __restrict__ wk, const float* __restrict__ bk,
    const float wc, const float wm)
{
    float d[9];
    d[0] = fmaxf(wk[0], p0) + bk[0];
    d[1] = fmaxf(wk[1], p1) + bk[1];
    d[2] = fmaxf(wk[2], p2) + bk[2];
    d[3] = fmaxf(wk[3], p3) + bk[3];
    d[4] = fmaxf(wk[4], p4) + bk[4];
    d[5] = fmaxf(wk[5], p5) + bk[5];
    d[6] = fmaxf(wk[6], p6) + bk[6];
    d[7] = fmaxf(wk[7], p7) + bk[7];
    d[8] = fmaxf(wk[8], p8) + bk[8];
    float sum = ((d[0] + d[1]) + (d[2] + d[3])) + ((d[5] + d[6]) + (d[7] + d[8])) + d[4];

    // median-of-9 (McGuire ShaderX6 network)
    #define S2(a,bb) { float t = d[a]; d[a] = fminf(d[a], d[bb]); d[bb] = fmaxf(t, d[bb]); }
    S2(0,3) S2(1,4) S2(2,5) S2(0,1) S2(0,2) S2(4,5) S2(3,5)
    S2(1,2) S2(3,4) S2(1,3) S2(1,6) S2(4,6) S2(2,6)
    S2(2,3) S2(4,7) S2(2,4) S2(3,7)
    S2(4,8) S2(3,8) S2(3,4)
    #undef S2

    return wc * p4 + wm * d[4] - sum - sum * (1.0f / 9.0f);
}

// Kernel 1: wave-autonomous register stencil. Lane l owns columns [2l, 2l+2).
// One wave sweeps an 8-row strip x 2 channels; 3-row window in registers;
// horizontal neighbors via shfl. No LDS, no barriers. Channel partials
// accumulated in registers, then atomicAdd into the per-pixel sum plane s.
__global__ __launch_bounds__(256) void partial_kernel(
    const float* __restrict__ x,
    const float* __restrict__ weight,
    const float* __restrict__ bias,
    const float* __restrict__ wcp,
    const float* __restrict__ wmp,
    float* __restrict__ s)
{
    const int tid   = threadIdx.x;
    const int lane  = tid & 63;
    const int strip = blockIdx.x * 4 + (tid >> 6);   // 0..15
    const int c0    = blockIdx.y * CPW;              // 0..62 step 2
    const int b     = blockIdx.z;

    const int row0 = strip * RS;
    const int col  = 2 * lane;

    float wk[9], bk[9];
    #pragma unroll
    for (int k = 0; k < 9; ++k) {
        wk[k] = sigmoidf_(weight[k]);
        bk[k] = sigmoidf_(bias[k]);
    }
    const float wc = wcp[0];
    const float wm = wmp[0];

    vfloat2 acc[RS];
    #pragma unroll
    for (int j = 0; j < RS; ++j) acc[j] = (vfloat2)(0.0f);

    #pragma unroll
    for (int cc = 0; cc < CPW; ++cc) {
        const float* base = x + ((size_t)b * CH + c0 + cc) * HW + col;

        // sliding 3-row window: (L, A, B, R) = left-halo, col, col+1, right-halo
        float L0, A0, B0, R0, L1, A1, B1, R1, L2, A2, B2, R2;

        // row loader: sigmoid first, zero-pad outside image (pad AFTER sigmoid)
        #define LOADROW(ri, Lr, Ar, Br, Rr)                                   \
        {                                                                     \
            const int  r_   = (ri);                                           \
            const bool okr  = (r_ >= 0) & (r_ < H);                           \
            const int  rcl  = min(max(r_, 0), H - 1);                         \
            vfloat2 v = *(const vfloat2*)(base + rcl * W);                    \
            Ar = okr ? sigmoidf_(v.x) : 0.0f;                                 \
            Br = okr ? sigmoidf_(v.y) : 0.0f;                                 \
            float lf = __shfl_up(Br, 1);                                      \
            float rg = __shfl_down(Ar, 1);                                    \
            Lr = (lane == 0)  ? 0.0f : lf;                                    \
            Rr = (lane == 63) ? 0.0f : rg;                                    \
        }

        LOADROW(row0 - 1, L0, A0, B0, R0);
        LOADROW(row0,     L1, A1, B1, R1);

        #pragma unroll
        for (int j = 0; j < RS; ++j) {
            LOADROW(row0 + j + 1, L2, A2, B2, R2);

            // pixel (row0+j, col):   window cols (col-1, col, col+1)
            acc[j].x += pixel_val(L0, A0, B0,
                                  L1, A1, B1,
                                  L2, A2, B2, wk, bk, wc, wm);
            // pixel (row0+j, col+1): window cols (col, col+1, col+2)
            acc[j].y += pixel_val(A0, B0, R0,
                                  A1, B1, R1,
                                  A2, B2, R2, wk, bk, wc, wm);

            L0 = L1; A0 = A1; B0 = B1; R0 = R1;
            L1 = L2; A1 = A2; B1 = B2; R1 = R2;
        }
        #undef LOADROW
    }

    float* sp = s + (size_t)b * HW + col;
    #pragma unroll
    for (int j = 0; j < RS; ++j) {
        atomicAdd(sp + (size_t)(row0 + j) * W,     acc[j].x);
        atomicAdd(sp + (size_t)(row0 + j) * W + 1, acc[j].y);
    }
}

// Kernel 2: read the per-pixel channel-sum plane (L2-hot, 512 KB) and
// broadcast to 16 of the 64 output planes per blockIdx.y group, dwordx4
// nontemporal stores (out is write-once, keep it out of L2).
__global__ __launch_bounds__(256) void broadcast_kernel(
    const float* __restrict__ s,
    float* __restrict__ out)
{
    const int g  = (blockIdx.x * 256 + threadIdx.x) * 4;   // pixel base
    const int b  = g >> 14;                                 // HW = 16384
    const int p  = g & (HW - 1);
    const int c0 = blockIdx.y * 16;

    vfloat4 v = *(const vfloat4*)(s + (size_t)b * HW + p);

    float* base = out + ((size_t)b * CH + c0) * HW + p;
    #pragma unroll
    for (int j = 0; j < 16; ++j)
        __builtin_nontemporal_store(v, (vfloat4*)(base + (size_t)j * HW));
}

extern "C" void kernel_launch(void* const* d_in, const int* in_sizes, int n_in,
                              void* d_out, int out_size, void* d_ws, size_t ws_size,
                              hipStream_t stream) {
    const float* x      = (const float*)d_in[0];
    const float* weight = (const float*)d_in[1];
    const float* bias   = (const float*)d_in[2];
    const float* wcp    = (const float*)d_in[3];
    const float* wmp    = (const float*)d_in[4];
    float* out = (float*)d_out;
    float* s   = (float*)d_ws;                    // 8*16384*4 B = 512 KiB

    hipMemsetAsync(s, 0, (size_t)BATCH * HW * sizeof(float), stream);

    dim3 grid1(NSTRIP / 4, CH / CPW, BATCH);      // 4 x 32 x 8 = 1024 blocks
    partial_kernel<<<grid1, 256, 0, stream>>>(x, weight, bias, wcp, wmp, s);

    dim3 grid2(BATCH * HW / (4 * 256), CH / 16);  // 128 x 4 = 512 blocks
    broadcast_kernel<<<grid2, 256, 0, stream>>>(s, out);
}

// Round 6
// 111.572 us; speedup vs baseline: 1.2293x; 1.2293x over previous
//
#include <hip/hip_runtime.h>

#define BATCH  8
#define CH     64
#define H      128
#define W      128
#define HW     (H * W)             // 16384
#define RS     8                   // rows per wave strip
#define CPW    2                   // channels per wave
#define NCHUNK (CH / CPW)          // 32 partial planes
#define NSTRIP (H / RS)            // 16

typedef float vfloat2 __attribute__((ext_vector_type(2)));
typedef float vfloat4 __attribute__((ext_vector_type(4)));

__device__ __forceinline__ float sigmoidf_(float v) {
    return 1.0f / (1.0f + __expf(-v));
}

// D_k = max(wk, p_k) + bk over 3x3 window; out = wc*center + wm*median - sum - sum/9
__device__ __forceinline__ float pixel_val(
    const float p0, const float p1, const float p2,
    const float p3, const float p4, const float p5,
    const float p6, const float p7, const float p8,
    const float* __restrict__ wk, const float* __restrict__ bk,
    const float wc, const float wm)
{
    float d[9];
    d[0] = fmaxf(wk[0], p0) + bk[0];
    d[1] = fmaxf(wk[1], p1) + bk[1];
    d[2] = fmaxf(wk[2], p2) + bk[2];
    d[3] = fmaxf(wk[3], p3) + bk[3];
    d[4] = fmaxf(wk[4], p4) + bk[4];
    d[5] = fmaxf(wk[5], p5) + bk[5];
    d[6] = fmaxf(wk[6], p6) + bk[6];
    d[7] = fmaxf(wk[7], p7) + bk[7];
    d[8] = fmaxf(wk[8], p8) + bk[8];
    float sum = ((d[0] + d[1]) + (d[2] + d[3])) + ((d[5] + d[6]) + (d[7] + d[8])) + d[4];

    // median-of-9 (McGuire ShaderX6 network)
    #define S2(a,bb) { float t = d[a]; d[a] = fminf(d[a], d[bb]); d[bb] = fmaxf(t, d[bb]); }
    S2(0,3) S2(1,4) S2(2,5) S2(0,1) S2(0,2) S2(4,5) S2(3,5)
    S2(1,2) S2(3,4) S2(1,3) S2(1,6) S2(4,6) S2(2,6)
    S2(2,3) S2(4,7) S2(2,4) S2(3,7)
    S2(4,8) S2(3,8) S2(3,4)
    #undef S2

    return wc * p4 + wm * d[4] - sum - sum * (1.0f / 9.0f);
}

// Kernel 1: wave-autonomous register stencil, NO barriers, NO atomics.
// Lane l owns columns [2l, 2l+2); a wave sweeps an 8-row strip x 2 channels.
// ALL 20 row-loads are issued into registers up front (one vmcnt-batched
// pipeline), then sigmoid + shfl + median run out of registers. The wave's
// channel-pair partial is stored exclusively into ws[b][chunk][h][w].
__global__ __launch_bounds__(256) void partial_kernel(
    const float* __restrict__ x,
    const float* __restrict__ weight,
    const float* __restrict__ bias,
    const float* __restrict__ wcp,
    const float* __restrict__ wmp,
    float* __restrict__ ws)
{
    const int tid   = threadIdx.x;
    const int lane  = tid & 63;
    const int strip = blockIdx.x * 4 + (tid >> 6);   // 0..15
    const int chnk  = blockIdx.y;                    // 0..31
    const int c0    = chnk * CPW;
    const int b     = blockIdx.z;

    const int row0 = strip * RS;
    const int col  = 2 * lane;

    float wk[9], bk[9];
    #pragma unroll
    for (int k = 0; k < 9; ++k) {
        wk[k] = sigmoidf_(weight[k]);
        bk[k] = sigmoidf_(bias[k]);
    }
    const float wc = wcp[0];
    const float wm = wmp[0];

    // ---- batch-issue ALL row loads first (independent addresses) ----
    vfloat2 raw[CPW][RS + 2];
    #pragma unroll
    for (int cc = 0; cc < CPW; ++cc) {
        const float* base = x + ((size_t)b * CH + c0 + cc) * HW + col;
        #pragma unroll
        for (int rr = 0; rr < RS + 2; ++rr) {
            const int r_  = row0 + rr - 1;
            const int rcl = min(max(r_, 0), H - 1);
            raw[cc][rr] = *(const vfloat2*)(base + rcl * W);
        }
    }

    vfloat2 acc[RS];
    #pragma unroll
    for (int j = 0; j < RS; ++j) acc[j] = (vfloat2)(0.0f);

    // sigmoid + pad + horizontal halo for one staged row
    #define SIGROW(cc, rr, Lr, Ar, Br, Rr)                                    \
    {                                                                         \
        const int  r_  = row0 + (rr) - 1;                                     \
        const bool okr = (r_ >= 0) & (r_ < H);                                \
        vfloat2 v = raw[cc][rr];                                              \
        Ar = okr ? sigmoidf_(v.x) : 0.0f;                                     \
        Br = okr ? sigmoidf_(v.y) : 0.0f;                                     \
        float lf = __shfl_up(Br, 1);                                          \
        float rg = __shfl_down(Ar, 1);                                        \
        Lr = (lane == 0)  ? 0.0f : lf;                                        \
        Rr = (lane == 63) ? 0.0f : rg;                                        \
    }

    #pragma unroll
    for (int cc = 0; cc < CPW; ++cc) {
        float L0, A0, B0, R0, L1, A1, B1, R1, L2, A2, B2, R2;
        SIGROW(cc, 0, L0, A0, B0, R0);
        SIGROW(cc, 1, L1, A1, B1, R1);

        #pragma unroll
        for (int j = 0; j < RS; ++j) {
            SIGROW(cc, j + 2, L2, A2, B2, R2);

            acc[j].x += pixel_val(L0, A0, B0,
                                  L1, A1, B1,
                                  L2, A2, B2, wk, bk, wc, wm);
            acc[j].y += pixel_val(A0, B0, R0,
                                  A1, B1, R1,
                                  A2, B2, R2, wk, bk, wc, wm);

            L0 = L1; A0 = A1; B0 = B1; R0 = R1;
            L1 = L2; A1 = A2; B1 = B2; R1 = R2;
        }
    }
    #undef SIGROW

    // exclusive partial-plane store (fire-and-forget dwordx2)
    float* op = ws + ((size_t)b * NCHUNK + chnk) * HW + (size_t)row0 * W + col;
    #pragma unroll
    for (int j = 0; j < RS; ++j)
        *(vfloat2*)(op + (size_t)j * W) = acc[j];
}

// Kernel 2: per pixel, sum the 32 partial planes (L2/L3-hot, 16 MB) and
// broadcast to 16 of the 64 output planes per blockIdx.y group; dwordx4
// nontemporal stores keep the 33.5 MB out-stream out of L2.
__global__ __launch_bounds__(256) void broadcast_kernel(
    const float* __restrict__ ws,
    float* __restrict__ out)
{
    const int g  = (blockIdx.x * 256 + threadIdx.x) * 4;   // pixel base
    const int b  = g >> 14;                                 // HW = 16384
    const int p  = g & (HW - 1);
    const int c0 = blockIdx.y * 16;

    const float* wsb = ws + (size_t)b * NCHUNK * HW + p;
    vfloat4 s = (vfloat4)(0.0f);
    #pragma unroll
    for (int k = 0; k < NCHUNK; ++k)
        s += *(const vfloat4*)(wsb + (size_t)k * HW);

    float* base = out + ((size_t)b * CH + c0) * HW + p;
    #pragma unroll
    for (int j = 0; j < 16; ++j)
        __builtin_nontemporal_store(s, (vfloat4*)(base + (size_t)j * HW));
}

extern "C" void kernel_launch(void* const* d_in, const int* in_sizes, int n_in,
                              void* d_out, int out_size, void* d_ws, size_t ws_size,
                              hipStream_t stream) {
    const float* x      = (const float*)d_in[0];
    const float* weight = (const float*)d_in[1];
    const float* bias   = (const float*)d_in[2];
    const float* wcp    = (const float*)d_in[3];
    const float* wmp    = (const float*)d_in[4];
    float* out = (float*)d_out;
    float* ws  = (float*)d_ws;                    // 8*32*16384*4 B = 16 MiB

    dim3 grid1(NSTRIP / 4, NCHUNK, BATCH);        // 4 x 32 x 8 = 1024 blocks
    partial_kernel<<<grid1, 256, 0, stream>>>(x, weight, bias, wcp, wmp, ws);

    dim3 grid2(BATCH * HW / (4 * 256), CH / 16);  // 128 x 4 = 512 blocks
    broadcast_kernel<<<grid2, 256, 0, stream>>>(ws, out);
}